// Round 1
// baseline (233.419 us; speedup 1.0000x reference)
//
#include <hip/hip_runtime.h>
#include <hip/hip_bf16.h>

// out[b,s] = cumsum_s( softplus(beta * c[b,s]) / beta ), fp32, B=4096, S=8192.
// One block per row; 256 threads; 32 elements/thread; 3-phase block scan.
// LDS layout: 2048 float4 chunks, XOR-swizzled (f ^ ((f>>3)&7)) so both the
// lane-linear (coalesced global) phase and the thread-contiguous phase are
// bank-balanced while keeping 16B alignment for ds_read_b128/ds_write_b128.

#define ROW_S 8192
#define BLOCK_T 256

__device__ __forceinline__ int swz(int f) { return f ^ ((f >> 3) & 7); }

__device__ __forceinline__ float softplus_step(float c, float beta, float inv_beta) {
    float tb = beta * c;
    float a  = fabsf(tb);
    float e  = __expf(-a);             // in (0,1], no overflow
    float l  = __logf(1.0f + e);       // log1p via log; abs err negligible vs threshold
    return (fmaxf(tb, 0.0f) + l) * inv_beta;
}

__global__ __launch_bounds__(BLOCK_T) void softplus_cumsum_kernel(
    const float* __restrict__ c,
    const float* __restrict__ beta_p,
    float* __restrict__ out)
{
    __shared__ float4 lds[ROW_S / 4];      // 2048 chunks = 32 KB
    __shared__ float  wave_sums[BLOCK_T / 64];

    const int t    = threadIdx.x;
    const int lane = t & 63;
    const int wave = t >> 6;
    const size_t row_base = (size_t)blockIdx.x * ROW_S;

    const float beta     = beta_p[0];
    const float inv_beta = 1.0f / beta;

    const float4* in4  = (const float4*)(c + row_base);
    float4*       out4 = (float4*)(out + row_base);

    // ---- Phase A: coalesced load + softplus + swizzled LDS store ----
    #pragma unroll
    for (int j = 0; j < 8; ++j) {
        int f = j * BLOCK_T + t;           // float4 chunk index, lane-linear
        float4 v = in4[f];
        float4 s;
        s.x = softplus_step(v.x, beta, inv_beta);
        s.y = softplus_step(v.y, beta, inv_beta);
        s.z = softplus_step(v.z, beta, inv_beta);
        s.w = softplus_step(v.w, beta, inv_beta);
        lds[swz(f)] = s;
    }
    __syncthreads();

    // ---- Phase B: per-thread sequential scan of its 32 contiguous elems ----
    float r[32];
    float run = 0.0f;
    #pragma unroll
    for (int k = 0; k < 8; ++k) {
        int f = t * 8 + k;                 // thread-contiguous chunks
        float4 v = lds[swz(f)];
        run += v.x; r[4 * k + 0] = run;
        run += v.y; r[4 * k + 1] = run;
        run += v.z; r[4 * k + 2] = run;
        run += v.w; r[4 * k + 3] = run;
    }
    const float total = run;

    // Wave-level inclusive scan of per-thread totals (width 64)
    float x = total;
    #pragma unroll
    for (int d = 1; d < 64; d <<= 1) {
        float y = __shfl_up(x, d, 64);
        if (lane >= d) x += y;
    }
    if (lane == 63) wave_sums[wave] = x;
    __syncthreads();

    // Block-level offset: exclusive wave prefix + exclusive thread prefix
    float off = x - total;                 // exclusive within wave
    #pragma unroll
    for (int w = 0; w < BLOCK_T / 64; ++w)
        if (w < wave) off += wave_sums[w];

    // ---- Phase C: write prefixed results back to swizzled LDS ----
    #pragma unroll
    for (int k = 0; k < 8; ++k) {
        int f = t * 8 + k;
        float4 s;
        s.x = r[4 * k + 0] + off;
        s.y = r[4 * k + 1] + off;
        s.z = r[4 * k + 2] + off;
        s.w = r[4 * k + 3] + off;
        lds[swz(f)] = s;
    }
    __syncthreads();

    // ---- Phase D: coalesced global store ----
    #pragma unroll
    for (int j = 0; j < 8; ++j) {
        int f = j * BLOCK_T + t;
        out4[f] = lds[swz(f)];
    }
}

extern "C" void kernel_launch(void* const* d_in, const int* in_sizes, int n_in,
                              void* d_out, int out_size, void* d_ws, size_t ws_size,
                              hipStream_t stream) {
    const float* c      = (const float*)d_in[0];
    const float* beta_p = (const float*)d_in[1];
    float*       out    = (float*)d_out;

    const int B = in_sizes[0] / ROW_S;     // 4096 rows
    softplus_cumsum_kernel<<<dim3(B), dim3(BLOCK_T), 0, stream>>>(c, beta_p, out);
}

// Round 2
// 233.055 us; speedup vs baseline: 1.0016x; 1.0016x over previous
//
#include <hip/hip_runtime.h>
#include <hip/hip_bf16.h>

// out[b,s] = cumsum_s( softplus(beta * c[b,s]) / beta ), fp32, B=4096, S=8192.
//
// R2 design: all data stays in registers; loads AND stores are lane-linear
// coalesced float4 (chunk f = j*256 + t). The cumsum is decomposed to match
// that layout:
//   - in-chunk (4 elem) inclusive scan in registers
//   - chunk order is j-major (all t of j=0, then j=1, ...), so the chunk-sum
//     prefix = running carry over j-groups + block-wide exclusive scan over t
//     within each j-group (wave shuffle scan + 4 wave totals in LDS).
// LDS: 8*4 floats. ONE barrier. No data LDS traffic (was 537 MB/launch in R1,
// with 3 barriers and 33 KB LDS capping occupancy at ~4 blocks/CU).

#define ROW_S   8192
#define BLOCK_T 256
#define NJ      (ROW_S / 4 / BLOCK_T)   // 8 float4 chunks per thread
#define NWAVE   (BLOCK_T / 64)          // 4 waves per block

__device__ __forceinline__ float softplus_step(float c, float beta, float inv_beta) {
    float tb = beta * c;
    float a  = fabsf(tb);
    float e  = __expf(-a);             // in (0,1], no overflow
    float l  = __logf(1.0f + e);       // log1p(exp(-|t|))
    return (fmaxf(tb, 0.0f) + l) * inv_beta;
}

__global__ __launch_bounds__(BLOCK_T) void softplus_cumsum_kernel(
    const float* __restrict__ c,
    const float* __restrict__ beta_p,
    float* __restrict__ out)
{
    __shared__ float wave_sums[NJ][NWAVE];   // 128 B total

    const int t    = threadIdx.x;
    const int lane = t & 63;
    const int wave = t >> 6;
    const size_t row_base = (size_t)blockIdx.x * ROW_S;

    const float beta     = beta_p[0];
    const float inv_beta = 1.0f / beta;

    const float4* __restrict__ in4  = (const float4*)(c + row_base);
    float4*       __restrict__ out4 = (float4*)(out + row_base);

    // ---- Issue all 8 coalesced loads up front (MLP) ----
    float4 v[NJ];
    #pragma unroll
    for (int j = 0; j < NJ; ++j)
        v[j] = in4[j * BLOCK_T + t];

    // ---- softplus + in-chunk inclusive scan; s[j] = chunk total ----
    float4 r[NJ];
    float  s[NJ];
    #pragma unroll
    for (int j = 0; j < NJ; ++j) {
        float a = softplus_step(v[j].x, beta, inv_beta);
        float b = softplus_step(v[j].y, beta, inv_beta);
        float d = softplus_step(v[j].z, beta, inv_beta);
        float e = softplus_step(v[j].w, beta, inv_beta);
        r[j].x = a;
        r[j].y = a + b;
        r[j].z = r[j].y + d;
        r[j].w = r[j].z + e;
        s[j]   = r[j].w;
    }

    // ---- 8 independent wave-inclusive shuffle scans of chunk sums ----
    float xscan[NJ];
    #pragma unroll
    for (int j = 0; j < NJ; ++j) {
        float x = s[j];
        #pragma unroll
        for (int d = 1; d < 64; d <<= 1) {
            float y = __shfl_up(x, d, 64);
            if (lane >= d) x += y;
        }
        xscan[j] = x;                         // inclusive over lanes of this wave
        if (lane == 63) wave_sums[j][wave] = x;
    }
    __syncthreads();

    // ---- Combine: carry over j-groups + wave-exclusive + lane-exclusive ----
    float carry = 0.0f;
    #pragma unroll
    for (int j = 0; j < NJ; ++j) {
        float woff = 0.0f, btot = 0.0f;
        #pragma unroll
        for (int w = 0; w < NWAVE; ++w) {
            float ws = wave_sums[j][w];       // broadcast read
            if (w < wave) woff += ws;         // wave-uniform predicate
            btot += ws;
        }
        const float off = carry + woff + (xscan[j] - s[j]);
        carry += btot;

        float4 o;
        o.x = r[j].x + off;
        o.y = r[j].y + off;
        o.z = r[j].z + off;
        o.w = r[j].w + off;
        out4[j * BLOCK_T + t] = o;            // coalesced store from regs
    }
}

extern "C" void kernel_launch(void* const* d_in, const int* in_sizes, int n_in,
                              void* d_out, int out_size, void* d_ws, size_t ws_size,
                              hipStream_t stream) {
    const float* c      = (const float*)d_in[0];
    const float* beta_p = (const float*)d_in[1];
    float*       out    = (float*)d_out;

    const int B = in_sizes[0] / ROW_S;     // 4096 rows
    softplus_cumsum_kernel<<<dim3(B), dim3(BLOCK_T), 0, stream>>>(c, beta_p, out);
}